// Round 20
// baseline (362.031 us; speedup 1.0000x reference)
//
#include <hip/hip_runtime.h>

typedef unsigned short u16;
typedef __attribute__((ext_vector_type(8))) short bf16x8;
typedef __attribute__((ext_vector_type(4))) float f32x4;
typedef __attribute__((ext_vector_type(16))) float f32x16;
typedef __attribute__((ext_vector_type(4))) unsigned short us4;
typedef __attribute__((ext_vector_type(8))) unsigned short us8;

#define S_LEN 2048
#define QKV_P 6144
#define WIN_SZ 1024
#define SCALE_F 0.08838834764831845f
#define LAMBDA_INIT_F 0.35550906759096925f
#define ONE_MINUS_LI_F 0.6444909324090308f

__device__ __forceinline__ u16 f2bf(float f) {
    union { float f; unsigned int u; } v; v.f = f;
    unsigned int u = v.u;
    return (u16)((u + 0x7fffu + ((u >> 16) & 1u)) >> 16);
}
__device__ __forceinline__ float bf2f(u16 u) {
    union { unsigned int u; float f; } v; v.u = ((unsigned int)u) << 16; return v.f;
}
__device__ __forceinline__ void gload16(const void* g, void* l) {
    __builtin_amdgcn_global_load_lds(
        (const __attribute__((address_space(1))) unsigned int*)g,
        (__attribute__((address_space(3))) unsigned int*)l, 16, 0, 0);
}

// ---------------------------------------------------------------------------
// f32 -> bf16 elementwise convert
// ---------------------------------------------------------------------------
__global__ __launch_bounds__(256)
void conv_f32_bf16(const float* __restrict__ src, u16* __restrict__ dst, int n4) {
    for (int i = blockIdx.x * 256 + threadIdx.x; i < n4; i += gridDim.x * 256) {
        float4 v = ((const float4*)src)[i];
        us4 h;
        h.x = f2bf(v.x); h.y = f2bf(v.y); h.z = f2bf(v.z); h.w = f2bf(v.w);
        ((us4*)dst)[i] = h;
    }
}

// ---------------------------------------------------------------------------
// Shared staging / fragment helpers.
// ---------------------------------------------------------------------------
template<int NR>
__device__ __forceinline__ void stage_half(const u16* __restrict__ src, int K,
                                           int gRowBase, int kcol0,
                                           u16* slot, int tid, int wid) {
#pragma unroll
    for (int g = 0; g < (NR + 127) / 128; ++g) {
        if (g * 128 + wid * 16 < NR) {   // wave-uniform
            int row = g * 128 + (tid >> 2);
            int cc = (tid & 3) ^ ((row >> 1) & 3);
            gload16(src + (size_t)(gRowBase + row) * K + kcol0 + cc * 8,
                    slot + g * 4096 + wid * 512);
        }
    }
}

// fragment read from a 32-K-col slot; logical chunk (0..3) XOR-swizzled by row
__device__ __forceinline__ bf16x8 ldfrag32(const u16* slot, int row, int chunk) {
    int pc = chunk ^ ((row >> 1) & 3);
    return *(const bf16x8*)(slot + row * 32 + pc * 8);
}

// ---------------------------------------------------------------------------
// QKV GEMM: 2-phase-per-K-tile 256x192, 8 waves as 4M x 2N (per-wave 64x96),
// mfma_f32_32x32x16_bf16 (2x3 frags of 32^2; 24 MFMA/wave/tile vs 48 of
// 16x16 -- 20% more FLOP/cyc per m119, half the issue slots). Round-18
// split-deep-wait scheme retained.
// C/D layout (guide-verified m74/m101): col=lane&31,
// row=(reg&3)+8*(reg>>2)+4*(lane>>5).
// ---------------------------------------------------------------------------
__device__ __forceinline__ void qkv_wait_deep(int wid) {
    if (wid < 4) asm volatile("s_waitcnt vmcnt(8)" ::: "memory");
    else         asm volatile("s_waitcnt vmcnt(6)" ::: "memory");
}
__device__ __forceinline__ void qkv_wait_half(int wid) {
    if (wid < 4) asm volatile("s_waitcnt vmcnt(4)" ::: "memory");
    else         asm volatile("s_waitcnt vmcnt(3)" ::: "memory");
}

__global__ __launch_bounds__(512)
__attribute__((amdgpu_waves_per_eu(2, 2)))
void gemm_qkv(const u16* __restrict__ A, const u16* __restrict__ W,
              const float* __restrict__ bias, u16* __restrict__ C,
              int M, int N, int K) {
    constexpr int BM = 256, BN = 192;
    constexpr int ASLOT = BM * 32;
    constexpr int BSLOT = BN * 32;
    __shared__ u16 lds[4 * ASLOT + 4 * BSLOT];

    const int tid = threadIdx.x;
    const int wid = tid >> 6, lane = tid & 63;
    const int wr = wid >> 1, wc = wid & 1;    // 4M x 2N, per-wave 64 x 96
    const int l31 = lane & 31, lhi = lane >> 5;

    const int x = blockIdx.x & 7, j = blockIdx.x >> 3;
    const int by = (x >> 2) * 4 + (j >> 3);
    const int bx = (x & 3) * 8 + (j & 7);
    const int rowBase = by * BM;
    const int colBase = bx * BN;

    const int NT = K >> 6;

    u16* const baseA = lds;
    u16* const baseB = lds + 4 * ASLOT;

    f32x16 acc[2][3] = {};

    stage_half<BM>(A, K, rowBase, 0,  baseA + 0 * ASLOT, tid, wid);
    stage_half<BN>(W, K, colBase, 0,  baseB + 0 * BSLOT, tid, wid);
    stage_half<BM>(A, K, rowBase, 32, baseA + 1 * ASLOT, tid, wid);
    stage_half<BN>(W, K, colBase, 32, baseB + 1 * BSLOT, tid, wid);
    stage_half<BM>(A, K, rowBase, 64, baseA + 2 * ASLOT, tid, wid);
    stage_half<BN>(W, K, colBase, 64, baseB + 2 * BSLOT, tid, wid);
    qkv_wait_half(wid);
    __builtin_amdgcn_s_barrier();

    for (int t = 0; t < NT; ++t) {
        const int b = t & 1;
        const int bn = b ^ 1;
        u16* const A0 = baseA + (b * 2 + 0) * ASLOT;
        u16* const A1 = baseA + (b * 2 + 1) * ASLOT;
        u16* const B0 = baseB + (b * 2 + 0) * BSLOT;
        u16* const B1 = baseB + (b * 2 + 1) * BSLOT;

        bf16x8 af[2][2], bfv[2][3];

        // ---- phase A: slot 0 (k-cols 0..31), 2 k-steps of 16
#pragma unroll
        for (int ks = 0; ks < 2; ++ks) {
#pragma unroll
            for (int m = 0; m < 2; ++m)
                af[ks][m] = ldfrag32(A0, wr * 64 + m * 32 + l31, ks * 2 + lhi);
#pragma unroll
            for (int n = 0; n < 3; ++n)
                bfv[ks][n] = ldfrag32(B0, wc * 96 + n * 32 + l31, ks * 2 + lhi);
        }
        if (t + 1 < NT) {
            stage_half<BM>(A, K, rowBase, (t + 1) * 64 + 32, baseA + (bn * 2 + 1) * ASLOT, tid, wid);
            stage_half<BN>(W, K, colBase, (t + 1) * 64 + 32, baseB + (bn * 2 + 1) * BSLOT, tid, wid);
        }
        __builtin_amdgcn_s_setprio(1);
#pragma unroll
        for (int ks = 0; ks < 2; ++ks)
#pragma unroll
            for (int m = 0; m < 2; ++m)
#pragma unroll
                for (int n = 0; n < 3; ++n)
                    acc[m][n] = __builtin_amdgcn_mfma_f32_32x32x16_bf16(af[ks][m], bfv[ks][n], acc[m][n], 0, 0, 0);
        __builtin_amdgcn_s_setprio(0);
        if (t == NT - 1) asm volatile("s_waitcnt vmcnt(0)" ::: "memory");
        else             qkv_wait_deep(wid);
        __builtin_amdgcn_s_barrier();

        // ---- phase B: slot 1 (k-cols 32..63)
#pragma unroll
        for (int ks = 0; ks < 2; ++ks) {
#pragma unroll
            for (int m = 0; m < 2; ++m)
                af[ks][m] = ldfrag32(A1, wr * 64 + m * 32 + l31, ks * 2 + lhi);
#pragma unroll
            for (int n = 0; n < 3; ++n)
                bfv[ks][n] = ldfrag32(B1, wc * 96 + n * 32 + l31, ks * 2 + lhi);
        }
        if (t + 2 < NT) {
            stage_half<BM>(A, K, rowBase, (t + 2) * 64, baseA + (b * 2 + 0) * ASLOT, tid, wid);
            stage_half<BN>(W, K, colBase, (t + 2) * 64, baseB + (b * 2 + 0) * BSLOT, tid, wid);
        }
        __builtin_amdgcn_s_setprio(1);
#pragma unroll
        for (int ks = 0; ks < 2; ++ks)
#pragma unroll
            for (int m = 0; m < 2; ++m)
#pragma unroll
                for (int n = 0; n < 3; ++n)
                    acc[m][n] = __builtin_amdgcn_mfma_f32_32x32x16_bf16(af[ks][m], bfv[ks][n], acc[m][n], 0, 0, 0);
        __builtin_amdgcn_s_setprio(0);
        if (t <= NT - 3)      qkv_wait_deep(wid);
        else if (t == NT - 2) qkv_wait_half(wid);
        else                  asm volatile("s_waitcnt vmcnt(0)" ::: "memory");
        __builtin_amdgcn_s_barrier();
    }

#pragma unroll
    for (int n = 0; n < 3; ++n) {
        int col = colBase + wc * 96 + n * 32 + l31;
        float bs = bias[col];
#pragma unroll
        for (int m = 0; m < 2; ++m)
#pragma unroll
            for (int r = 0; r < 16; ++r) {
                int rowi = rowBase + wr * 64 + m * 32 + (r & 3) + 8 * (r >> 2) + 4 * lhi;
                C[(size_t)rowi * N + col] = f2bf(acc[m][n][r] + bs);
            }
    }
}

// ---------------------------------------------------------------------------
// OUT GEMM: 3-buffer single-barrier-per-K-tile 128x256, 8 waves (2M x 4N,
// per-wave 64x64), mfma 32x32x16 (2x2 frags; 16 MFMA/wave/tile).
// ---------------------------------------------------------------------------
__global__ __launch_bounds__(512)
__attribute__((amdgpu_waves_per_eu(2, 2)))
void gemm_out(const u16* __restrict__ A, const u16* __restrict__ W,
              const float* __restrict__ bias, float* __restrict__ C,
              int M, int N, int K) {
    constexpr int BM = 128, BN = 256;
    constexpr int AT = BM * 64;       // 8192 u16 per A buffer
    constexpr int BT = BN * 64;       // 16384 u16 per B buffer
    __shared__ u16 lds[3 * (AT + BT)];   // 144 KB

    const int tid = threadIdx.x;
    const int wid = tid >> 6, lane = tid & 63;
    const int wr = wid >> 2, wc = wid & 3;    // per-wave 64x64
    const int l31 = lane & 31, lhi = lane >> 5;

    const int x = blockIdx.x & 7, j = blockIdx.x >> 3;
    const int by = (x >> 2) * 8 + (j & 7);
    const int bx = (x & 3) * 4 + (j >> 3);
    const int rowBase = by * BM, colBase = bx * BN;
    const int NT = K >> 6;

    u16* const baseA = lds;
    u16* const baseB = lds + 3 * AT;

    f32x16 acc[2][2] = {};

#define STAGE3(T, nb)                                                          \
    {                                                                          \
        stage_half<BM>(A, K, rowBase, (T) * 64,      baseA + (nb) * AT, tid, wid);           \
        stage_half<BM>(A, K, rowBase, (T) * 64 + 32, baseA + (nb) * AT + BM * 32, tid, wid); \
        stage_half<BN>(W, K, colBase, (T) * 64,      baseB + (nb) * BT, tid, wid);           \
        stage_half<BN>(W, K, colBase, (T) * 64 + 32, baseB + (nb) * BT + BN * 32, tid, wid); \
    }

    STAGE3(0, 0);
    STAGE3(1, 1);
    asm volatile("s_waitcnt vmcnt(6)" ::: "memory");
    __builtin_amdgcn_s_barrier();

    int cur = 0;
    for (int t = 0; t < NT; ++t) {
        u16* const Ab = baseA + cur * AT;
        u16* const Bb = baseB + cur * BT;

        bf16x8 a_[4][2], b_[4][2];   // [half*2+ks][frag]
#pragma unroll
        for (int h = 0; h < 2; ++h)
#pragma unroll
            for (int ks = 0; ks < 2; ++ks) {
                const u16* Ah = Ab + h * (BM * 32);
                const u16* Bh = Bb + h * (BN * 32);
#pragma unroll
                for (int m = 0; m < 2; ++m)
                    a_[h * 2 + ks][m] = ldfrag32(Ah, wr * 64 + m * 32 + l31, ks * 2 + lhi);
#pragma unroll
                for (int n = 0; n < 2; ++n)
                    b_[h * 2 + ks][n] = ldfrag32(Bh, wc * 64 + n * 32 + l31, ks * 2 + lhi);
            }
        if (t + 2 < NT) {
            int nb = cur + 2; if (nb >= 3) nb -= 3;
            STAGE3(t + 2, nb);
        }
        __builtin_amdgcn_s_setprio(1);
#pragma unroll
        for (int s = 0; s < 4; ++s)
#pragma unroll
            for (int m = 0; m < 2; ++m)
#pragma unroll
                for (int n = 0; n < 2; ++n)
                    acc[m][n] = __builtin_amdgcn_mfma_f32_32x32x16_bf16(a_[s][m], b_[s][n], acc[m][n], 0, 0, 0);
        __builtin_amdgcn_s_setprio(0);
        if (t <= NT - 3)      asm volatile("s_waitcnt vmcnt(6)" ::: "memory");
        else if (t == NT - 2) asm volatile("s_waitcnt vmcnt(0)" ::: "memory");
        __builtin_amdgcn_s_barrier();
        cur = cur + 1; if (cur == 3) cur = 0;
    }
#undef STAGE3

#pragma unroll
    for (int n = 0; n < 2; ++n) {
        int col = colBase + wc * 64 + n * 32 + l31;
        float bs = bias[col];
#pragma unroll
        for (int m = 0; m < 2; ++m)
#pragma unroll
            for (int r = 0; r < 16; ++r) {
                int rowi = rowBase + wr * 64 + m * 32 + (r & 3) + 8 * (r >> 2) + 4 * lhi;
                C[(size_t)rowi * N + col] = acc[m][n][r] + bs;
            }
    }
}

// ---------------------------------------------------------------------------
// RoPE in-place on bf16 qkv.
// ---------------------------------------------------------------------------
__global__ __launch_bounds__(256)
void rope_bf16(u16* __restrict__ qkv, const int* __restrict__ positions) {
    const int row = blockIdx.x;
    const float pos = (float)positions[row];
    for (int idx = threadIdx.x; idx < 640; idx += 256) {
        int head = idx >> 4;
        int g = idx & 15;
        int base = (head < 32) ? head * 128 : 4096 + (head - 32) * 128;
        u16* p = qkv + (size_t)row * QKV_P + base + g * 4;
        us4 x1 = *(us4*)p;
        us4 x2 = *(us4*)(p + 64);
#pragma unroll
        for (int j = 0; j < 4; ++j) {
            float inv_freq = __expf(-(float)(g * 4 + j) * (9.210340371976184f / 64.0f));
            float ang = pos * inv_freq;
            float s, c;
            sincosf(ang, &s, &c);
            float a = bf2f(x1[j]), b = bf2f(x2[j]);
            x1[j] = f2bf(a * c - b * s);
            x2[j] = f2bf(b * c + a * s);
        }
        *(us4*)p = x1;
        *(us4*)(p + 64) = x2;
    }
}

// ---------------------------------------------------------------------------
// V transpose: qkv V-region -> vt[a][d][s].
// ---------------------------------------------------------------------------
__global__ __launch_bounds__(256)
void vtrans(const u16* __restrict__ qkv, u16* __restrict__ vt) {
    __shared__ u16 T[128 * 72];
    const int s0 = blockIdx.x * 64;
    const int a = blockIdx.y;
    const u16* src = qkv + 5120 + a * 128;
#pragma unroll
    for (int it = 0; it < 4; ++it) {
        int idx = it * 256 + threadIdx.x;
        int s = idx >> 4;
        int c8 = idx & 15;
        us8 v = *(const us8*)(src + (size_t)(s0 + s) * QKV_P + c8 * 8);
        int sc = s >> 3, su = s & 7;
#pragma unroll
        for (int j = 0; j < 8; ++j) {
            int d = c8 * 8 + j;
            T[d * 72 + ((sc ^ ((d >> 3) & 7)) * 8 + su)] = v[j];
        }
    }
    __syncthreads();
#pragma unroll
    for (int it = 0; it < 4; ++it) {
        int idx = it * 256 + threadIdx.x;
        int d = idx >> 3, sc = idx & 7;
        us8 v = *(const us8*)&T[d * 72 + ((sc ^ ((d >> 3) & 7)) * 8)];
        *(us8*)(vt + (size_t)a * 262144 + (size_t)d * 2048 + s0 + sc * 8) = v;
    }
}

// ---------------------------------------------------------------------------
// STREAM-SPLIT dual-stream sliding-window flash attention + fused RMS-norm.
// (unchanged from round 13)
// ---------------------------------------------------------------------------
__global__ __launch_bounds__(512)
__attribute__((amdgpu_waves_per_eu(2, 2)))
void attn_bf16(const u16* __restrict__ qkv, const u16* __restrict__ vtg,
               u16* __restrict__ attnb,
               const float* __restrict__ lq1, const float* __restrict__ lk1,
               const float* __restrict__ lq2, const float* __restrict__ lk2,
               const float* __restrict__ subln) {
    __shared__ u16 smem[73728];   // 144 KB
#define KBUF(b, st) (smem + ((b) * 2 + (st)) * 8192)
#define VBUF(b, st) (smem + 32768 + ((b) * 2 + (st)) * 8192)

    const int tid = threadIdx.x;
    const int w = tid >> 6, lane = tid & 63;
    const int g = w & 3, sid = w >> 2;
    const int l15 = lane & 15, l4 = lane >> 4;
    u16* const Pw = smem + 65536 + w * 1024;

    int qb, h;
    {
        int i = blockIdx.x;
        if (i < 256) { qb = 16 + (i & 15); h = i >> 4; }
        else         { int j = i - 256; qb = j & 15; h = j >> 4; }
    }
    const int q0 = qb * 64;
    const int a1 = 2 * (h >> 2), a2 = a1 + 1;

    bf16x8 qf[4];
    {
        int qrow = q0 + g * 16 + l15;
        const u16* qp = qkv + (size_t)qrow * QKV_P + (2 * h + sid) * 128;
#pragma unroll
        for (int kk = 0; kk < 4; ++kk)
            qf[kk] = *(const bf16x8*)(qp + kk * 32 + l4 * 8);
    }

    bf16x8 onesf;
#pragma unroll
    for (int j = 0; j < 8; ++j) onesf[j] = (short)0x3F80;

    f32x4 aV1[8] = {}, aV2[8] = {};
    f32x4 l_acc = {};
    float m[4];
#pragma unroll
    for (int r = 0; r < 4; ++r) m[r] = -1e30f;

    const int kr4 = lane >> 4, kc = lane & 15;
    const int vd8 = lane >> 3, vc = lane & 7;

    const int tbeg = (qb >= 16) ? (qb - 16) : 0;
    const int tend = qb;

#define STAGE_TILE(T, NB)                                                      \
    {                                                                          \
        const int kv0s = (T) * 64;                                             \
        _Pragma("unroll")                                                      \
        for (int s2 = 0; s2 < 2; ++s2) {                                       \
            int ch = w * 2 + s2;                                               \
            int krow = ch * 4 + kr4;                                           \
            int kcs = (kc ^ (krow & 7)) * 8;                                   \
            const u16* kbase = qkv + (size_t)(kv0s + krow) * QKV_P + 4096;     \
            gload16(kbase + a1 * 128 + kcs, KBUF(NB, 0) + ch * 512);           \
            gload16(kbase + a2 * 128 + kcs, KBUF(NB, 1) + ch * 512);           \
            int vdrow = ch * 8 + vd8;                                          \
            int vcs = (vc ^ (vdrow & 7)) * 8;                                  \
            const u16* vbase = vtg + (size_t)vdrow * 2048 + kv0s + vcs;        \
            gload16(vbase + (size_t)a1 * 262144, VBUF(NB, 0) + ch * 512);      \
            gload16(vbase + (size_t)a2 * 262144, VBUF(NB, 1) + ch * 512);      \
        }                                                                      \
    }

    STAGE_TILE(tbeg, 0);
    asm volatile("s_waitcnt vmcnt(0)" ::: "memory");
    __builtin_amdgcn_s_barrier();
    asm volatile("" ::: "memory");

    int cb = 0;
    for (int t = tbeg; t <= tend; ++t) {
        const int kv0 = t * 64;

        if (t < tend) STAGE_TILE(t + 1, cb ^ 1);

        // --- QK^T (this wave's stream only)
        f32x4 sc[4];
        const u16* Kc = KBUF(cb, sid);
        __builtin_amdgcn_s_setprio(1);
#pragma unroll
        for (int c = 0; c < 4; ++c) {
            f32x4 s1 = {0.f, 0.f, 0.f, 0.f};
#pragma unroll
            for (int kk = 0; kk < 4; ++kk) {
                int off = (c * 16 + l15) * 128 + (((kk * 4 + l4) ^ (l15 & 7)) * 8);
                s1 = __builtin_amdgcn_mfma_f32_16x16x32_bf16(qf[kk], *(const bf16x8*)&Kc[off], s1, 0, 0, 0);
            }
            sc[c] = s1;
        }
        __builtin_amdgcn_s_setprio(0);

        const bool dz = (t == tend);
        const bool wz = (qb >= 16) && (t <= tbeg + 1);
        if (dz) {
#pragma unroll
            for (int c = 0; c < 4; ++c) {
                int j = kv0 + c * 16 + l15;
#pragma unroll
                for (int r = 0; r < 4; ++r) {
                    int i = q0 + g * 16 + l4 * 4 + r;
                    if (j > i) sc[c][r] = -1e30f;
                }
            }
        } else if (wz) {
#pragma unroll
            for (int c = 0; c < 4; ++c) {
                int j = kv0 + c * 16 + l15;
#pragma unroll
                for (int r = 0; r < 4; ++r) {
                    int i = q0 + g * 16 + l4 * 4 + r;
                    if (i - j >= WIN_SZ) sc[c][r] = -1e30f;
                }
            }
        }

        // --- defer-max: cheap local check; full shfl reduce only on trigger
        float lmax[4];
#pragma unroll
        for (int r = 0; r < 4; ++r)
            lmax[r] = fmaxf(fmaxf(sc[0][r], sc[1][r]), fmaxf(sc[2][r], sc[3][r]));
        bool need = false;
#pragma unroll
        for (int r = 0; r < 4; ++r)
            need = need || (lmax[r] > m[r] + 32.0f);
        if (__any(need)) {
            float rmax[4];
#pragma unroll
            for (int r = 0; r < 4; ++r) rmax[r] = lmax[r];
#pragma unroll
            for (int msk = 1; msk < 16; msk <<= 1)
#pragma unroll
                for (int r = 0; r < 4; ++r)
                    rmax[r] = fmaxf(rmax[r], __shfl_xor(rmax[r], msk));
            float fr[4];
#pragma unroll
            for (int r = 0; r < 4; ++r) {
                float nm = fmaxf(m[r], rmax[r]);
                fr[r] = __expf((m[r] - nm) * SCALE_F);
                m[r] = nm;
                l_acc[r] *= fr[r];
            }
#pragma unroll
            for (int f = 0; f < 8; ++f)
#pragma unroll
                for (int r = 0; r < 4; ++r) {
                    aV1[f][r] *= fr[r];
                    aV2[f][r] *= fr[r];
                }
        }

        // --- P = exp((s-m)*SCALE); P -> wave-private LDS (swizzled)
#pragma unroll
        for (int c = 0; c < 4; ++c) {
            int col = c * 16 + l15;
#pragma unroll
            for (int r = 0; r < 4; ++r) {
                int prow = l4 * 4 + r;
                float p = __expf((sc[c][r] - m[r]) * SCALE_F);
                if (wz && (m[r] < -1e29f)) p = 0.f;   // fully-masked row
                int pco = ((col >> 3) ^ (prow & 7)) * 8 + (col & 7);
                Pw[prow * 64 + pco] = f2bf(p);
            }
        }

        // --- PV vs both V halves + rowsum via MFMA(P, ones)
        const u16* V0 = VBUF(cb, 0);
        const u16* V1 = VBUF(cb, 1);
        __builtin_amdgcn_s_setprio(1);
#pragma unroll
        for (int kk = 0; kk < 2; ++kk) {
            int pch = ((kk * 4 + l4) ^ (l15 & 7)) * 8;
            bf16x8 pa = *(const bf16x8*)&Pw[l15 * 64 + pch];
            l_acc = __builtin_amdgcn_mfma_f32_16x16x32_bf16(pa, onesf, l_acc, 0, 0, 0);
#pragma unroll
            for (int f = 0; f < 8; ++f) {
                int off = (f * 16 + l15) * 64 + (((kk * 4 + l4) ^ (l15 & 7)) * 8);
                aV1[f] = __builtin_amdgcn_mfma_f32_16x16x32_bf16(pa, *(const bf16x8*)&V0[off], aV1[f], 0, 0, 0);
                aV2[f] = __builtin_amdgcn_mfma_f32_16x16x32_bf16(pa, *(const bf16x8*)&V1[off], aV2[f], 0, 0, 0);
            }
        }
        __builtin_amdgcn_s_setprio(0);

        asm volatile("s_waitcnt vmcnt(0)" ::: "memory");
        __builtin_amdgcn_s_barrier();
        asm volatile("" ::: "memory");
        cb ^= 1;
    }

    // lambda scalar (all waves)
    float s1v = lq1[lane] * lk1[lane] + lq1[lane + 64] * lk1[lane + 64];
    float s2v = lq2[lane] * lk2[lane] + lq2[lane + 64] * lk2[lane + 64];
#pragma unroll
    for (int msk = 1; msk < 64; msk <<= 1) {
        s1v += __shfl_xor(s1v, msk);
        s2v += __shfl_xor(s2v, msk);
    }
    const float lam = __expf(s1v) - __expf(s2v) + LAMBDA_INIT_F;

    // cross-stream combine via f32 LDS overlay (stride 264 -> conflict-free)
    float* const Cmb = (float*)smem;
    if (sid == 1) {
#pragma unroll
        for (int r = 0; r < 4; ++r) {
            float inv2 = lam / l_acc[r];
            int row = g * 16 + l4 * 4 + r;
#pragma unroll
            for (int f = 0; f < 8; ++f) {
                Cmb[row * 264 + f * 16 + l15]       = aV1[f][r] * inv2;
                Cmb[row * 264 + 128 + f * 16 + l15] = aV2[f][r] * inv2;
            }
        }
    }
    __syncthreads();
    if (sid == 0) {
        float sw0[8], sw1[8];
#pragma unroll
        for (int f = 0; f < 8; ++f) {
            sw0[f] = subln[f * 16 + l15];
            sw1[f] = subln[128 + f * 16 + l15];
        }
#pragma unroll
        for (int r = 0; r < 4; ++r) {
            float inv1 = 1.0f / l_acc[r];
            int row = g * 16 + l4 * 4 + r;
            float o0[8], o1[8];
            float ssq = 0.f;
#pragma unroll
            for (int f = 0; f < 8; ++f) {
                o0[f] = aV1[f][r] * inv1 - Cmb[row * 264 + f * 16 + l15];
                o1[f] = aV2[f][r] * inv1 - Cmb[row * 264 + 128 + f * 16 + l15];
                ssq += o0[f] * o0[f] + o1[f] * o1[f];
            }
#pragma unroll
            for (int msk = 1; msk < 16; msk <<= 1) ssq += __shfl_xor(ssq, msk);
            float scale = rsqrtf(ssq * (1.0f / 256.0f) + 1e-5f) * ONE_MINUS_LI_F;
            u16* op = attnb + (size_t)(q0 + row) * 4096 + h * 256;
#pragma unroll
            for (int f = 0; f < 8; ++f) {
                op[f * 16 + l15]       = f2bf(o0[f] * scale * sw0[f]);
                op[128 + f * 16 + l15] = f2bf(o1[f] * scale * sw1[f]);
            }
        }
    }
#undef STAGE_TILE
#undef KBUF
#undef VBUF
}

// ---------------------------------------------------------------------------
extern "C" void kernel_launch(void* const* d_in, const int* in_sizes, int n_in,
                              void* d_out, int out_size, void* d_ws, size_t ws_size,
                              hipStream_t stream) {
    const float* hidden    = (const float*)d_in[0];
    const int*   positions = (const int*)d_in[1];
    const float* Wqkv_w    = (const float*)d_in[2];
    const float* Wqkv_b    = (const float*)d_in[3];
    const float* out_w     = (const float*)d_in[4];
    const float* out_b     = (const float*)d_in[5];
    const float* lq1       = (const float*)d_in[6];
    const float* lk1       = (const float*)d_in[7];
    const float* lq2       = (const float*)d_in[8];
    const float* lk2       = (const float*)d_in[9];
    const float* subln     = (const float*)d_in[10];
    float* out = (float*)d_out;

    u16* ws0   = (u16*)d_ws;
    u16* hb    = ws0;
    u16* wqb   = ws0 + 8388608;
    u16* qkvb  = ws0 + 33554432;
    u16* attnb = ws0;
    u16* owb   = ws0 + 8388608;
    u16* vt    = ws0 + 25165824;

    conv_f32_bf16<<<2048, 256, 0, stream>>>(hidden, hb, 2048 * 4096 / 4);
    conv_f32_bf16<<<2048, 256, 0, stream>>>(Wqkv_w, wqb, 6144 * 4096 / 4);

    // QKV: M=2048, N=6144, BM=256/BN=192 -> 8 x 32 = 256 blocks
    gemm_qkv<<<256, 512, 0, stream>>>(hb, wqb, Wqkv_b, qkvb, 2048, 6144, 4096);

    rope_bf16<<<S_LEN, 256, 0, stream>>>(qkvb, positions);
    vtrans<<<dim3(32, 8), 256, 0, stream>>>(qkvb, vt);

    conv_f32_bf16<<<2048, 256, 0, stream>>>(out_w, owb, 4096 * 4096 / 4);

    // attention: 512 blocks (32 qb x 16 h, heavy-first remap), 8 waves
    attn_bf16<<<512, 512, 0, stream>>>(qkvb, vt, attnb, lq1, lk1, lq2, lk2, subln);

    // out: M=2048, N=4096, BM=128/BN=256, 3-buffer 1-barrier -> 16x16 = 256 blocks
    gemm_out<<<256, 512, 0, stream>>>(attnb, owb, out_b, out, 2048, 4096, 4096);
}

// Round 21
// 331.529 us; speedup vs baseline: 1.0920x; 1.0920x over previous
//
#include <hip/hip_runtime.h>

typedef unsigned short u16;
typedef __attribute__((ext_vector_type(8))) short bf16x8;
typedef __attribute__((ext_vector_type(4))) float f32x4;
typedef __attribute__((ext_vector_type(4))) unsigned short us4;
typedef __attribute__((ext_vector_type(8))) unsigned short us8;

#define S_LEN 2048
#define QKV_P 6144
#define WIN_SZ 1024
#define SCALE_F 0.08838834764831845f
#define LAMBDA_INIT_F 0.35550906759096925f
#define ONE_MINUS_LI_F 0.6444909324090308f

__device__ __forceinline__ u16 f2bf(float f) {
    union { float f; unsigned int u; } v; v.f = f;
    unsigned int u = v.u;
    return (u16)((u + 0x7fffu + ((u >> 16) & 1u)) >> 16);
}
__device__ __forceinline__ float bf2f(u16 u) {
    union { unsigned int u; float f; } v; v.u = ((unsigned int)u) << 16; return v.f;
}
__device__ __forceinline__ void gload16(const void* g, void* l) {
    __builtin_amdgcn_global_load_lds(
        (const __attribute__((address_space(1))) unsigned int*)g,
        (__attribute__((address_space(3))) unsigned int*)l, 16, 0, 0);
}

// ---------------------------------------------------------------------------
// f32 -> bf16 elementwise convert
// ---------------------------------------------------------------------------
__global__ __launch_bounds__(256)
void conv_f32_bf16(const float* __restrict__ src, u16* __restrict__ dst, int n4) {
    for (int i = blockIdx.x * 256 + threadIdx.x; i < n4; i += gridDim.x * 256) {
        float4 v = ((const float4*)src)[i];
        us4 h;
        h.x = f2bf(v.x); h.y = f2bf(v.y); h.z = f2bf(v.z); h.w = f2bf(v.w);
        ((us4*)dst)[i] = h;
    }
}

// ---------------------------------------------------------------------------
// Shared staging / fragment helpers. (16x16x32 MFMA layout: chunk = l4
// contributes 4 values across the wave -> conflict-free reads; the 32x32
// shape's lhi-only spread is a structural 4-way conflict -- round 20.)
// ---------------------------------------------------------------------------
template<int NR>
__device__ __forceinline__ void stage_half(const u16* __restrict__ src, int K,
                                           int gRowBase, int kcol0,
                                           u16* slot, int tid, int wid) {
#pragma unroll
    for (int g = 0; g < (NR + 127) / 128; ++g) {
        if (g * 128 + wid * 16 < NR) {   // wave-uniform
            int row = g * 128 + (tid >> 2);
            int cc = (tid & 3) ^ ((row >> 1) & 3);
            gload16(src + (size_t)(gRowBase + row) * K + kcol0 + cc * 8,
                    slot + g * 4096 + wid * 512);
        }
    }
}

__device__ __forceinline__ bf16x8 ldfrag(const u16* slot, int row, int l4) {
    int pc = l4 ^ ((row >> 1) & 3);
    return *(const bf16x8*)(slot + row * 32 + pc * 8);
}

// ---------------------------------------------------------------------------
// QKV GEMM: 2-phase-per-K-tile 256x192, 8 waves (2M x 4N), 16x16x32 MFMA,
// round-18 split-deep-wait scheme.
// ---------------------------------------------------------------------------
__device__ __forceinline__ void qkv_wait_deep(int wid) {
    if (wid < 4) asm volatile("s_waitcnt vmcnt(8)" ::: "memory");
    else         asm volatile("s_waitcnt vmcnt(6)" ::: "memory");
}
__device__ __forceinline__ void qkv_wait_half(int wid) {
    if (wid < 4) asm volatile("s_waitcnt vmcnt(4)" ::: "memory");
    else         asm volatile("s_waitcnt vmcnt(3)" ::: "memory");
}

__global__ __launch_bounds__(512)
__attribute__((amdgpu_waves_per_eu(2, 2)))
void gemm_qkv(const u16* __restrict__ A, const u16* __restrict__ W,
              const float* __restrict__ bias, u16* __restrict__ C,
              int M, int N, int K) {
    constexpr int BM = 256, NF = 3, BN = NF * 64;
    constexpr int ASLOT = BM * 32;
    constexpr int BSLOT = NF * 2048;
    constexpr int MFRAG = BM / 32;
    __shared__ u16 lds[4 * ASLOT + 4 * BSLOT];

    const int tid = threadIdx.x;
    const int wid = tid >> 6, lane = tid & 63;
    const int wr = wid >> 2, wc = wid & 3;
    const int l15 = lane & 15, l4 = lane >> 4;

    const int x = blockIdx.x & 7, j = blockIdx.x >> 3;
    const int by = (x >> 2) * 4 + (j >> 3);
    const int bx = (x & 3) * 8 + (j & 7);
    const int rowBase = by * BM;
    const int colBase = bx * BN;

    const int NT = K >> 6;

    u16* const baseA = lds;
    u16* const baseB = lds + 4 * ASLOT;

    f32x4 acc[MFRAG][NF] = {};

    stage_half<BM>(A, K, rowBase, 0,  baseA + 0 * ASLOT, tid, wid);
    stage_half<BN>(W, K, colBase, 0,  baseB + 0 * BSLOT, tid, wid);
    stage_half<BM>(A, K, rowBase, 32, baseA + 1 * ASLOT, tid, wid);
    stage_half<BN>(W, K, colBase, 32, baseB + 1 * BSLOT, tid, wid);
    stage_half<BM>(A, K, rowBase, 64, baseA + 2 * ASLOT, tid, wid);
    stage_half<BN>(W, K, colBase, 64, baseB + 2 * BSLOT, tid, wid);
    qkv_wait_half(wid);
    __builtin_amdgcn_s_barrier();

    for (int t = 0; t < NT; ++t) {
        const int b = t & 1;
        const int bn = b ^ 1;
        u16* const A0 = baseA + (b * 2 + 0) * ASLOT;
        u16* const A1 = baseA + (b * 2 + 1) * ASLOT;
        u16* const B0 = baseB + (b * 2 + 0) * BSLOT;
        u16* const B1 = baseB + (b * 2 + 1) * BSLOT;

        bf16x8 af[MFRAG], bfv[NF];

        // ---- phase A: kk0
#pragma unroll
        for (int m = 0; m < MFRAG; ++m) af[m] = ldfrag(A0, wr * (BM / 2) + m * 16 + l15, l4);
#pragma unroll
        for (int n = 0; n < NF; ++n) bfv[n] = ldfrag(B0, wc * (NF * 16) + n * 16 + l15, l4);
        if (t + 1 < NT) {
            stage_half<BM>(A, K, rowBase, (t + 1) * 64 + 32, baseA + (bn * 2 + 1) * ASLOT, tid, wid);
            stage_half<BN>(W, K, colBase, (t + 1) * 64 + 32, baseB + (bn * 2 + 1) * BSLOT, tid, wid);
        }
        __builtin_amdgcn_s_setprio(1);
#pragma unroll
        for (int m = 0; m < MFRAG; ++m)
#pragma unroll
            for (int n = 0; n < NF; ++n)
                acc[m][n] = __builtin_amdgcn_mfma_f32_16x16x32_bf16(af[m], bfv[n], acc[m][n], 0, 0, 0);
        __builtin_amdgcn_s_setprio(0);
        if (t == NT - 1) asm volatile("s_waitcnt vmcnt(0)" ::: "memory");
        else             qkv_wait_deep(wid);
        __builtin_amdgcn_s_barrier();

        // ---- phase B: kk1
#pragma unroll
        for (int m = 0; m < MFRAG; ++m) af[m] = ldfrag(A1, wr * (BM / 2) + m * 16 + l15, l4);
#pragma unroll
        for (int n = 0; n < NF; ++n) bfv[n] = ldfrag(B1, wc * (NF * 16) + n * 16 + l15, l4);
        if (t + 2 < NT) {
            stage_half<BM>(A, K, rowBase, (t + 2) * 64, baseA + (b * 2 + 0) * ASLOT, tid, wid);
            stage_half<BN>(W, K, colBase, (t + 2) * 64, baseB + (b * 2 + 0) * BSLOT, tid, wid);
        }
        __builtin_amdgcn_s_setprio(1);
#pragma unroll
        for (int m = 0; m < MFRAG; ++m)
#pragma unroll
            for (int n = 0; n < NF; ++n)
                acc[m][n] = __builtin_amdgcn_mfma_f32_16x16x32_bf16(af[m], bfv[n], acc[m][n], 0, 0, 0);
        __builtin_amdgcn_s_setprio(0);
        if (t <= NT - 3)      qkv_wait_deep(wid);
        else if (t == NT - 2) qkv_wait_half(wid);
        else                  asm volatile("s_waitcnt vmcnt(0)" ::: "memory");
        __builtin_amdgcn_s_barrier();
    }

#pragma unroll
    for (int n = 0; n < NF; ++n) {
        int col = colBase + wc * (NF * 16) + n * 16 + l15;
        float bs = bias[col];
#pragma unroll
        for (int m = 0; m < MFRAG; ++m)
#pragma unroll
            for (int rr = 0; rr < 4; ++rr) {
                int rowi = rowBase + wr * (BM / 2) + m * 16 + l4 * 4 + rr;
                C[(size_t)rowi * N + col] = f2bf(acc[m][n][rr] + bs);
            }
    }
}

// ---------------------------------------------------------------------------
// OUT GEMM: 3-buffer single-barrier-per-K-tile 128x256, 8 waves (2M x 4N,
// per-wave 64x64), 16x16x32 MFMA.
// ---------------------------------------------------------------------------
__global__ __launch_bounds__(512)
__attribute__((amdgpu_waves_per_eu(2, 2)))
void gemm_out(const u16* __restrict__ A, const u16* __restrict__ W,
              const float* __restrict__ bias, float* __restrict__ C,
              int M, int N, int K) {
    constexpr int BM = 128, BN = 256;
    constexpr int AT = BM * 64;       // 8192 u16 per A buffer
    constexpr int BT = BN * 64;       // 16384 u16 per B buffer
    __shared__ u16 lds[3 * (AT + BT)];   // 144 KB

    const int tid = threadIdx.x;
    const int wid = tid >> 6, lane = tid & 63;
    const int wr = wid >> 2, wc = wid & 3;    // per-wave 64x64
    const int l15 = lane & 15, l4 = lane >> 4;

    const int x = blockIdx.x & 7, j = blockIdx.x >> 3;
    const int by = (x >> 2) * 8 + (j & 7);
    const int bx = (x & 3) * 4 + (j >> 3);
    const int rowBase = by * BM, colBase = bx * BN;
    const int NT = K >> 6;

    u16* const baseA = lds;
    u16* const baseB = lds + 3 * AT;

    f32x4 acc[4][4] = {};

#define STAGE3(T, nb)                                                          \
    {                                                                          \
        stage_half<BM>(A, K, rowBase, (T) * 64,      baseA + (nb) * AT, tid, wid);           \
        stage_half<BM>(A, K, rowBase, (T) * 64 + 32, baseA + (nb) * AT + BM * 32, tid, wid); \
        stage_half<BN>(W, K, colBase, (T) * 64,      baseB + (nb) * BT, tid, wid);           \
        stage_half<BN>(W, K, colBase, (T) * 64 + 32, baseB + (nb) * BT + BN * 32, tid, wid); \
    }

    STAGE3(0, 0);
    STAGE3(1, 1);
    asm volatile("s_waitcnt vmcnt(6)" ::: "memory");
    __builtin_amdgcn_s_barrier();

    int cur = 0;
    for (int t = 0; t < NT; ++t) {
        u16* const Ab = baseA + cur * AT;
        u16* const Bb = baseB + cur * BT;

        bf16x8 a0[4], a1[4], b0[4], b1[4];
#pragma unroll
        for (int m2 = 0; m2 < 4; ++m2) {
            a0[m2] = ldfrag(Ab,           wr * 64 + m2 * 16 + l15, l4);
            a1[m2] = ldfrag(Ab + BM * 32, wr * 64 + m2 * 16 + l15, l4);
            b0[m2] = ldfrag(Bb,           wc * 64 + m2 * 16 + l15, l4);
            b1[m2] = ldfrag(Bb + BN * 32, wc * 64 + m2 * 16 + l15, l4);
        }
        if (t + 2 < NT) {
            int nb = cur + 2; if (nb >= 3) nb -= 3;
            STAGE3(t + 2, nb);
        }
        __builtin_amdgcn_s_setprio(1);
#pragma unroll
        for (int m2 = 0; m2 < 4; ++m2)
#pragma unroll
            for (int n = 0; n < 4; ++n) {
                acc[m2][n] = __builtin_amdgcn_mfma_f32_16x16x32_bf16(a0[m2], b0[n], acc[m2][n], 0, 0, 0);
                acc[m2][n] = __builtin_amdgcn_mfma_f32_16x16x32_bf16(a1[m2], b1[n], acc[m2][n], 0, 0, 0);
            }
        __builtin_amdgcn_s_setprio(0);
        if (t <= NT - 3)      asm volatile("s_waitcnt vmcnt(6)" ::: "memory");
        else if (t == NT - 2) asm volatile("s_waitcnt vmcnt(0)" ::: "memory");
        __builtin_amdgcn_s_barrier();
        cur = cur + 1; if (cur == 3) cur = 0;
    }
#undef STAGE3

#pragma unroll
    for (int n = 0; n < 4; ++n) {
        int col = colBase + wc * 64 + n * 16 + l15;
        float bs = bias[col];
#pragma unroll
        for (int m2 = 0; m2 < 4; ++m2)
#pragma unroll
            for (int rr = 0; rr < 4; ++rr) {
                int rowi = rowBase + wr * 64 + m2 * 16 + l4 * 4 + rr;
                C[(size_t)rowi * N + col] = acc[m2][n][rr] + bs;
            }
    }
}

// ---------------------------------------------------------------------------
// RoPE in-place on bf16 qkv.
// ---------------------------------------------------------------------------
__global__ __launch_bounds__(256)
void rope_bf16(u16* __restrict__ qkv, const int* __restrict__ positions) {
    const int row = blockIdx.x;
    const float pos = (float)positions[row];
    for (int idx = threadIdx.x; idx < 640; idx += 256) {
        int head = idx >> 4;
        int g = idx & 15;
        int base = (head < 32) ? head * 128 : 4096 + (head - 32) * 128;
        u16* p = qkv + (size_t)row * QKV_P + base + g * 4;
        us4 x1 = *(us4*)p;
        us4 x2 = *(us4*)(p + 64);
#pragma unroll
        for (int j = 0; j < 4; ++j) {
            float inv_freq = __expf(-(float)(g * 4 + j) * (9.210340371976184f / 64.0f));
            float ang = pos * inv_freq;
            float s, c;
            sincosf(ang, &s, &c);
            float a = bf2f(x1[j]), b = bf2f(x2[j]);
            x1[j] = f2bf(a * c - b * s);
            x2[j] = f2bf(b * c + a * s);
        }
        *(us4*)p = x1;
        *(us4*)(p + 64) = x2;
    }
}

// ---------------------------------------------------------------------------
// V transpose: qkv V-region -> vt[a][d][s].
// ---------------------------------------------------------------------------
__global__ __launch_bounds__(256)
void vtrans(const u16* __restrict__ qkv, u16* __restrict__ vt) {
    __shared__ u16 T[128 * 72];
    const int s0 = blockIdx.x * 64;
    const int a = blockIdx.y;
    const u16* src = qkv + 5120 + a * 128;
#pragma unroll
    for (int it = 0; it < 4; ++it) {
        int idx = it * 256 + threadIdx.x;
        int s = idx >> 4;
        int c8 = idx & 15;
        us8 v = *(const us8*)(src + (size_t)(s0 + s) * QKV_P + c8 * 8);
        int sc = s >> 3, su = s & 7;
#pragma unroll
        for (int j = 0; j < 8; ++j) {
            int d = c8 * 8 + j;
            T[d * 72 + ((sc ^ ((d >> 3) & 7)) * 8 + su)] = v[j];
        }
    }
    __syncthreads();
#pragma unroll
    for (int it = 0; it < 4; ++it) {
        int idx = it * 256 + threadIdx.x;
        int d = idx >> 3, sc = idx & 7;
        us8 v = *(const us8*)&T[d * 72 + ((sc ^ ((d >> 3) & 7)) * 8)];
        *(us8*)(vt + (size_t)a * 262144 + (size_t)d * 2048 + s0 + sc * 8) = v;
    }
}

// ---------------------------------------------------------------------------
// STREAM-SPLIT dual-stream sliding-window flash attention + fused RMS-norm.
// (unchanged from round 13)
// ---------------------------------------------------------------------------
__global__ __launch_bounds__(512)
__attribute__((amdgpu_waves_per_eu(2, 2)))
void attn_bf16(const u16* __restrict__ qkv, const u16* __restrict__ vtg,
               u16* __restrict__ attnb,
               const float* __restrict__ lq1, const float* __restrict__ lk1,
               const float* __restrict__ lq2, const float* __restrict__ lk2,
               const float* __restrict__ subln) {
    __shared__ u16 smem[73728];   // 144 KB
#define KBUF(b, st) (smem + ((b) * 2 + (st)) * 8192)
#define VBUF(b, st) (smem + 32768 + ((b) * 2 + (st)) * 8192)

    const int tid = threadIdx.x;
    const int w = tid >> 6, lane = tid & 63;
    const int g = w & 3, sid = w >> 2;
    const int l15 = lane & 15, l4 = lane >> 4;
    u16* const Pw = smem + 65536 + w * 1024;

    int qb, h;
    {
        int i = blockIdx.x;
        if (i < 256) { qb = 16 + (i & 15); h = i >> 4; }
        else         { int j = i - 256; qb = j & 15; h = j >> 4; }
    }
    const int q0 = qb * 64;
    const int a1 = 2 * (h >> 2), a2 = a1 + 1;

    bf16x8 qf[4];
    {
        int qrow = q0 + g * 16 + l15;
        const u16* qp = qkv + (size_t)qrow * QKV_P + (2 * h + sid) * 128;
#pragma unroll
        for (int kk = 0; kk < 4; ++kk)
            qf[kk] = *(const bf16x8*)(qp + kk * 32 + l4 * 8);
    }

    bf16x8 onesf;
#pragma unroll
    for (int j = 0; j < 8; ++j) onesf[j] = (short)0x3F80;

    f32x4 aV1[8] = {}, aV2[8] = {};
    f32x4 l_acc = {};
    float m[4];
#pragma unroll
    for (int r = 0; r < 4; ++r) m[r] = -1e30f;

    const int kr4 = lane >> 4, kc = lane & 15;
    const int vd8 = lane >> 3, vc = lane & 7;

    const int tbeg = (qb >= 16) ? (qb - 16) : 0;
    const int tend = qb;

#define STAGE_TILE(T, NB)                                                      \
    {                                                                          \
        const int kv0s = (T) * 64;                                             \
        _Pragma("unroll")                                                      \
        for (int s2 = 0; s2 < 2; ++s2) {                                       \
            int ch = w * 2 + s2;                                               \
            int krow = ch * 4 + kr4;                                           \
            int kcs = (kc ^ (krow & 7)) * 8;                                   \
            const u16* kbase = qkv + (size_t)(kv0s + krow) * QKV_P + 4096;     \
            gload16(kbase + a1 * 128 + kcs, KBUF(NB, 0) + ch * 512);           \
            gload16(kbase + a2 * 128 + kcs, KBUF(NB, 1) + ch * 512);           \
            int vdrow = ch * 8 + vd8;                                          \
            int vcs = (vc ^ (vdrow & 7)) * 8;                                  \
            const u16* vbase = vtg + (size_t)vdrow * 2048 + kv0s + vcs;        \
            gload16(vbase + (size_t)a1 * 262144, VBUF(NB, 0) + ch * 512);      \
            gload16(vbase + (size_t)a2 * 262144, VBUF(NB, 1) + ch * 512);      \
        }                                                                      \
    }

    STAGE_TILE(tbeg, 0);
    asm volatile("s_waitcnt vmcnt(0)" ::: "memory");
    __builtin_amdgcn_s_barrier();
    asm volatile("" ::: "memory");

    int cb = 0;
    for (int t = tbeg; t <= tend; ++t) {
        const int kv0 = t * 64;

        if (t < tend) STAGE_TILE(t + 1, cb ^ 1);

        // --- QK^T (this wave's stream only)
        f32x4 sc[4];
        const u16* Kc = KBUF(cb, sid);
        __builtin_amdgcn_s_setprio(1);
#pragma unroll
        for (int c = 0; c < 4; ++c) {
            f32x4 s1 = {0.f, 0.f, 0.f, 0.f};
#pragma unroll
            for (int kk = 0; kk < 4; ++kk) {
                int off = (c * 16 + l15) * 128 + (((kk * 4 + l4) ^ (l15 & 7)) * 8);
                s1 = __builtin_amdgcn_mfma_f32_16x16x32_bf16(qf[kk], *(const bf16x8*)&Kc[off], s1, 0, 0, 0);
            }
            sc[c] = s1;
        }
        __builtin_amdgcn_s_setprio(0);

        const bool dz = (t == tend);
        const bool wz = (qb >= 16) && (t <= tbeg + 1);
        if (dz) {
#pragma unroll
            for (int c = 0; c < 4; ++c) {
                int j = kv0 + c * 16 + l15;
#pragma unroll
                for (int r = 0; r < 4; ++r) {
                    int i = q0 + g * 16 + l4 * 4 + r;
                    if (j > i) sc[c][r] = -1e30f;
                }
            }
        } else if (wz) {
#pragma unroll
            for (int c = 0; c < 4; ++c) {
                int j = kv0 + c * 16 + l15;
#pragma unroll
                for (int r = 0; r < 4; ++r) {
                    int i = q0 + g * 16 + l4 * 4 + r;
                    if (i - j >= WIN_SZ) sc[c][r] = -1e30f;
                }
            }
        }

        // --- defer-max: cheap local check; full shfl reduce only on trigger
        float lmax[4];
#pragma unroll
        for (int r = 0; r < 4; ++r)
            lmax[r] = fmaxf(fmaxf(sc[0][r], sc[1][r]), fmaxf(sc[2][r], sc[3][r]));
        bool need = false;
#pragma unroll
        for (int r = 0; r < 4; ++r)
            need = need || (lmax[r] > m[r] + 32.0f);
        if (__any(need)) {
            float rmax[4];
#pragma unroll
            for (int r = 0; r < 4; ++r) rmax[r] = lmax[r];
#pragma unroll
            for (int msk = 1; msk < 16; msk <<= 1)
#pragma unroll
                for (int r = 0; r < 4; ++r)
                    rmax[r] = fmaxf(rmax[r], __shfl_xor(rmax[r], msk));
            float fr[4];
#pragma unroll
            for (int r = 0; r < 4; ++r) {
                float nm = fmaxf(m[r], rmax[r]);
                fr[r] = __expf((m[r] - nm) * SCALE_F);
                m[r] = nm;
                l_acc[r] *= fr[r];
            }
#pragma unroll
            for (int f = 0; f < 8; ++f)
#pragma unroll
                for (int r = 0; r < 4; ++r) {
                    aV1[f][r] *= fr[r];
                    aV2[f][r] *= fr[r];
                }
        }

        // --- P = exp((s-m)*SCALE); P -> wave-private LDS (swizzled)
#pragma unroll
        for (int c = 0; c < 4; ++c) {
            int col = c * 16 + l15;
#pragma unroll
            for (int r = 0; r < 4; ++r) {
                int prow = l4 * 4 + r;
                float p = __expf((sc[c][r] - m[r]) * SCALE_F);
                if (wz && (m[r] < -1e29f)) p = 0.f;   // fully-masked row
                int pco = ((col >> 3) ^ (prow & 7)) * 8 + (col & 7);
                Pw[prow * 64 + pco] = f2bf(p);
            }
        }

        // --- PV vs both V halves + rowsum via MFMA(P, ones)
        const u16* V0 = VBUF(cb, 0);
        const u16* V1 = VBUF(cb, 1);
        __builtin_amdgcn_s_setprio(1);
#pragma unroll
        for (int kk = 0; kk < 2; ++kk) {
            int pch = ((kk * 4 + l4) ^ (l15 & 7)) * 8;
            bf16x8 pa = *(const bf16x8*)&Pw[l15 * 64 + pch];
            l_acc = __builtin_amdgcn_mfma_f32_16x16x32_bf16(pa, onesf, l_acc, 0, 0, 0);
#pragma unroll
            for (int f = 0; f < 8; ++f) {
                int off = (f * 16 + l15) * 64 + (((kk * 4 + l4) ^ (l15 & 7)) * 8);
                aV1[f] = __builtin_amdgcn_mfma_f32_16x16x32_bf16(pa, *(const bf16x8*)&V0[off], aV1[f], 0, 0, 0);
                aV2[f] = __builtin_amdgcn_mfma_f32_16x16x32_bf16(pa, *(const bf16x8*)&V1[off], aV2[f], 0, 0, 0);
            }
        }
        __builtin_amdgcn_s_setprio(0);

        asm volatile("s_waitcnt vmcnt(0)" ::: "memory");
        __builtin_amdgcn_s_barrier();
        asm volatile("" ::: "memory");
        cb ^= 1;
    }

    // lambda scalar (all waves)
    float s1v = lq1[lane] * lk1[lane] + lq1[lane + 64] * lk1[lane + 64];
    float s2v = lq2[lane] * lk2[lane] + lq2[lane + 64] * lk2[lane + 64];
#pragma unroll
    for (int msk = 1; msk < 64; msk <<= 1) {
        s1v += __shfl_xor(s1v, msk);
        s2v += __shfl_xor(s2v, msk);
    }
    const float lam = __expf(s1v) - __expf(s2v) + LAMBDA_INIT_F;

    // cross-stream combine via f32 LDS overlay (stride 264 -> conflict-free)
    float* const Cmb = (float*)smem;
    if (sid == 1) {
#pragma unroll
        for (int r = 0; r < 4; ++r) {
            float inv2 = lam / l_acc[r];
            int row = g * 16 + l4 * 4 + r;
#pragma unroll
            for (int f = 0; f < 8; ++f) {
                Cmb[row * 264 + f * 16 + l15]       = aV1[f][r] * inv2;
                Cmb[row * 264 + 128 + f * 16 + l15] = aV2[f][r] * inv2;
            }
        }
    }
    __syncthreads();
    if (sid == 0) {
        float sw0[8], sw1[8];
#pragma unroll
        for (int f = 0; f < 8; ++f) {
            sw0[f] = subln[f * 16 + l15];
            sw1[f] = subln[128 + f * 16 + l15];
        }
#pragma unroll
        for (int r = 0; r < 4; ++r) {
            float inv1 = 1.0f / l_acc[r];
            int row = g * 16 + l4 * 4 + r;
            float o0[8], o1[8];
            float ssq = 0.f;
#pragma unroll
            for (int f = 0; f < 8; ++f) {
                o0[f] = aV1[f][r] * inv1 - Cmb[row * 264 + f * 16 + l15];
                o1[f] = aV2[f][r] * inv1 - Cmb[row * 264 + 128 + f * 16 + l15];
                ssq += o0[f] * o0[f] + o1[f] * o1[f];
            }
#pragma unroll
            for (int msk = 1; msk < 16; msk <<= 1) ssq += __shfl_xor(ssq, msk);
            float scale = rsqrtf(ssq * (1.0f / 256.0f) + 1e-5f) * ONE_MINUS_LI_F;
            u16* op = attnb + (size_t)(q0 + row) * 4096 + h * 256;
#pragma unroll
            for (int f = 0; f < 8; ++f) {
                op[f * 16 + l15]       = f2bf(o0[f] * scale * sw0[f]);
                op[128 + f * 16 + l15] = f2bf(o1[f] * scale * sw1[f]);
            }
        }
    }
#undef STAGE_TILE
#undef KBUF
#undef VBUF
}

// ---------------------------------------------------------------------------
extern "C" void kernel_launch(void* const* d_in, const int* in_sizes, int n_in,
                              void* d_out, int out_size, void* d_ws, size_t ws_size,
                              hipStream_t stream) {
    const float* hidden    = (const float*)d_in[0];
    const int*   positions = (const int*)d_in[1];
    const float* Wqkv_w    = (const float*)d_in[2];
    const float* Wqkv_b    = (const float*)d_in[3];
    const float* out_w     = (const float*)d_in[4];
    const float* out_b     = (const float*)d_in[5];
    const float* lq1       = (const float*)d_in[6];
    const float* lk1       = (const float*)d_in[7];
    const float* lq2       = (const float*)d_in[8];
    const float* lk2       = (const float*)d_in[9];
    const float* subln     = (const float*)d_in[10];
    float* out = (float*)d_out;

    u16* ws0   = (u16*)d_ws;
    u16* hb    = ws0;
    u16* wqb   = ws0 + 8388608;
    u16* qkvb  = ws0 + 33554432;
    u16* attnb = ws0;
    u16* owb   = ws0 + 8388608;
    u16* vt    = ws0 + 25165824;

    conv_f32_bf16<<<2048, 256, 0, stream>>>(hidden, hb, 2048 * 4096 / 4);
    conv_f32_bf16<<<2048, 256, 0, stream>>>(Wqkv_w, wqb, 6144 * 4096 / 4);

    // QKV: M=2048, N=6144, BM=256/BN=192 -> 8 x 32 = 256 blocks
    gemm_qkv<<<256, 512, 0, stream>>>(hb, wqb, Wqkv_b, qkvb, 2048, 6144, 4096);

    rope_bf16<<<S_LEN, 256, 0, stream>>>(qkvb, positions);
    vtrans<<<dim3(32, 8), 256, 0, stream>>>(qkvb, vt);

    conv_f32_bf16<<<2048, 256, 0, stream>>>(out_w, owb, 4096 * 4096 / 4);

    // attention: 512 blocks (32 qb x 16 h, heavy-first remap), 8 waves
    attn_bf16<<<512, 512, 0, stream>>>(qkvb, vt, attnb, lq1, lk1, lq2, lk2, subln);

    // out: M=2048, N=4096, BM=128/BN=256, 3-buffer 1-barrier -> 16x16 = 256 blocks
    gemm_out<<<256, 512, 0, stream>>>(attnb, owb, out_b, out, 2048, 4096, 4096);
}